// Round 7
// baseline (296.707 us; speedup 1.0000x reference)
//
#include <hip/hip_runtime.h>
#include <hip/hip_bf16.h>

typedef __attribute__((ext_vector_type(8))) _Float16 f16x8;
typedef __attribute__((ext_vector_type(2))) __fp16 fp16x2;
typedef __attribute__((ext_vector_type(4))) float f32x4;
typedef unsigned short u16;
typedef unsigned int u32;

#define S_LEN 2048
#define NH    16
#define DK    64
#define DMODEL 1024
#define LSTR  40   // LDS row stride (f16 elems) for GEMM tiles

union F16U { _Float16 h; u16 u; };
__device__ __forceinline__ u16 f2h(float f) {
    F16U v; v.h = (_Float16)f; return v.u;
}
union PKU { fp16x2 h; u32 u; };
__device__ __forceinline__ u32 pkrtz(float a, float b) {
    PKU v; v.h = __builtin_amdgcn_cvt_pkrtz(a, b); return v.u;
}

// ------------------------- fused prep kernel -------------------------------
// blk [0,2048): x -> fp16. blk [2048,3072): W^T fp16 [n][k]. blk [3072,3328): bias table.
__global__ __launch_bounds__(256) void prep_kernel(
    const float* __restrict__ x,
    const float* __restrict__ Wq, const float* __restrict__ Wk,
    const float* __restrict__ Wv, const float* __restrict__ Wo,
    const float* __restrict__ rel_emb,
    u16* __restrict__ Xf, u16* __restrict__ WT, float* __restrict__ tab)
{
    __shared__ __align__(16) float T[64 * 68];
    const int blk = blockIdx.x;
    const int tid = threadIdx.x;

    if (blk < 2048) {
        long i8 = ((long)blk * 256 + tid) * 8;
        float4 a = *(const float4*)&x[i8];
        float4 b = *(const float4*)&x[i8 + 4];
        *(ushort4*)&Xf[i8] =
            make_ushort4(f2h(a.x), f2h(a.y), f2h(a.z), f2h(a.w));
        *(ushort4*)&Xf[i8 + 4] =
            make_ushort4(f2h(b.x), f2h(b.y), f2h(b.z), f2h(b.w));
    } else if (blk < 3072) {
        int id = blk - 2048;
        int z = id >> 8, rem = id & 255;
        int k0 = (rem >> 4) * 64, n0 = (rem & 15) * 64;
        const float* src = (z == 0) ? Wq : (z == 1) ? Wk : (z == 2) ? Wv : Wo;
        u16* dT = WT + (long)z * 1048576;
        #pragma unroll
        for (int u = 0; u < 4; u++) {
            int w = tid + u * 256;
            int r = w >> 4, c4 = (w & 15) * 4;
            *(float4*)&T[r * 68 + c4] =
                *(const float4*)&src[(long)(k0 + r) * DMODEL + n0 + c4];
        }
        __syncthreads();
        #pragma unroll
        for (int u = 0; u < 4; u++) {
            int w = tid + u * 256;
            int n = w >> 4, kc = (w & 15) * 4;
            *(ushort4*)&dT[(long)(n0 + n) * DMODEL + k0 + kc] = make_ushort4(
                f2h(T[(kc + 0) * 68 + n]), f2h(T[(kc + 1) * 68 + n]),
                f2h(T[(kc + 2) * 68 + n]), f2h(T[(kc + 3) * 68 + n]));
        }
    } else {
        // bias table: integer-exact replica of reference fp32 bucket math
        int idx = (blk - 3072) * 256 + tid;   // 0..65535
        int h = idx >> 12;
        int t = idx & 4095;
        int n = -(t - 2048);       // q - k
        int ret = 0;
        if (n < 0) { ret = 16; n = -n; }
        int inner;
        if (n < 8) {
            inner = n;
        } else {
            inner = 8 + (n >= 12) + (n >= 16) + (n >= 23) + (n >= 32)
                      + (n >= 46) + (n >= 64) + (n >= 91);
            if (inner > 15) inner = 15;
        }
        tab[h * 4096 + t] = rel_emb[(ret + inner) * NH + h];
    }
}

// ------------------------- MFMA QKV GEMM (fp16, 1-pass) --------------------
// z=0: Q -> [B,H,S,Dk]; z=1: K -> [B,H,S,Dk]  (transposed-C: ushort4 stores)
// z=2: V -> V^T [B,H,Dk,S]                     (normal-C: ushort4 along S)
__global__ __launch_bounds__(256, 3) void gemm_qkv_mfma(
    const u16* __restrict__ Xf, const u16* __restrict__ WT,
    u16* __restrict__ Qf, u16* __restrict__ Kf, u16* __restrict__ VT)
{
    const int z = blockIdx.z;
    const u16* BT = WT + (long)z * 1048576;

    __shared__ __align__(16) u16 Ah[128 * LSTR], Bh[128 * LSTR];

    const int tid = threadIdx.x;
    const int wv = tid >> 6, lane = tid & 63;
    const int g = lane >> 4, li = lane & 15;
    const int wr = wv >> 1, wc = wv & 1;
    const int bm = blockIdx.y * 128, bn = blockIdx.x * 128;

    f32x4 acc[4][4];
    #pragma unroll
    for (int i = 0; i < 4; i++)
        #pragma unroll
        for (int j = 0; j < 4; j++) acc[i][j] = (f32x4){0.f, 0.f, 0.f, 0.f};

    for (int k0 = 0; k0 < DMODEL; k0 += 32) {
        #pragma unroll
        for (int u = 0; u < 2; u++) {
            int w = tid + u * 256;
            int row = w >> 2, q8 = (w & 3) * 8;
            *(uint4*)&Ah[row * LSTR + q8] =
                *(const uint4*)&Xf[(long)(bm + row) * DMODEL + k0 + q8];
            *(uint4*)&Bh[row * LSTR + q8] =
                *(const uint4*)&BT[(long)(bn + row) * DMODEL + k0 + q8];
        }
        __syncthreads();

        f16x8 a_h[4], b_h[4];
        #pragma unroll
        for (int i = 0; i < 4; i++)
            a_h[i] = *(const f16x8*)&Ah[(wr * 64 + i * 16 + li) * LSTR + g * 8];
        #pragma unroll
        for (int j = 0; j < 4; j++)
            b_h[j] = *(const f16x8*)&Bh[(wc * 64 + j * 16 + li) * LSTR + g * 8];
        if (z == 2) {
            #pragma unroll
            for (int i = 0; i < 4; i++)
                #pragma unroll
                for (int j = 0; j < 4; j++)
                    acc[i][j] = __builtin_amdgcn_mfma_f32_16x16x32_f16(
                        a_h[i], b_h[j], acc[i][j], 0, 0, 0);
        } else {
            // swapped operands -> C^T: col=li = s-row, row=g*4+r = d-col
            #pragma unroll
            for (int i = 0; i < 4; i++)
                #pragma unroll
                for (int j = 0; j < 4; j++)
                    acc[i][j] = __builtin_amdgcn_mfma_f32_16x16x32_f16(
                        b_h[j], a_h[i], acc[i][j], 0, 0, 0);
        }
        __syncthreads();
    }

    if (z == 2) {
        // V^T epilogue: [B,H,Dk,S]; r-contiguous along S -> ushort4 stores
        #pragma unroll
        for (int i = 0; i < 4; i++) {
            int s_base = bm + wr * 64 + i * 16 + g * 4;
            int bb = s_base >> 11, s = s_base & 2047;
            #pragma unroll
            for (int j = 0; j < 4; j++) {
                int gcol = bn + wc * 64 + j * 16 + li;
                int hh = gcol >> 6, d = gcol & 63;
                long idx = (((long)(bb * NH + hh)) * DK + d) * S_LEN + s;
                *(ushort4*)&VT[idx] = make_ushort4(
                    f2h(acc[i][j][0]), f2h(acc[i][j][1]),
                    f2h(acc[i][j][2]), f2h(acc[i][j][3]));
            }
        }
    } else {
        // transposed-C epilogue: 4 consecutive d per lane -> ushort4 stores
        u16* O = (z == 0) ? Qf : Kf;
        #pragma unroll
        for (int i = 0; i < 4; i++) {
            int srow = bm + wr * 64 + i * 16 + li;
            int bb = srow >> 11, s = srow & 2047;
            #pragma unroll
            for (int j = 0; j < 4; j++) {
                int dcol = bn + wc * 64 + j * 16 + g * 4;
                int hh = dcol >> 6, d = dcol & 63;
                long idx = (((long)(bb * NH + hh)) * S_LEN + s) * DK + d;
                *(ushort4*)&O[idx] = make_ushort4(
                    f2h(acc[i][j][0]), f2h(acc[i][j][1]),
                    f2h(acc[i][j][2]), f2h(acc[i][j][3]));
            }
        }
    }
}

// ------------------------- MFMA output GEMM (fp16, C^T) --------------------
__global__ __launch_bounds__(256, 3) void gemm_out_mfma(
    const u16* __restrict__ Ab, const u16* __restrict__ WT,
    float* __restrict__ O)
{
    const u16* BT = WT + 3L * 1048576;   // wo fp16 plane
    __shared__ __align__(16) u16 Ah[128 * LSTR], Bh[128 * LSTR];

    const int tid = threadIdx.x;
    const int wv = tid >> 6, lane = tid & 63;
    const int g = lane >> 4, li = lane & 15;
    const int wr = wv >> 1, wc = wv & 1;
    const int bm = blockIdx.y * 128, bn = blockIdx.x * 128;

    f32x4 acc[4][4];
    #pragma unroll
    for (int i = 0; i < 4; i++)
        #pragma unroll
        for (int j = 0; j < 4; j++) acc[i][j] = (f32x4){0.f, 0.f, 0.f, 0.f};

    for (int k0 = 0; k0 < DMODEL; k0 += 32) {
        #pragma unroll
        for (int u = 0; u < 2; u++) {
            int w = tid + u * 256;
            int row = w >> 2, q8 = (w & 3) * 8;
            *(uint4*)&Ah[row * LSTR + q8] =
                *(const uint4*)&Ab[(long)(bm + row) * DMODEL + k0 + q8];
            *(uint4*)&Bh[row * LSTR + q8] =
                *(const uint4*)&BT[(long)(bn + row) * DMODEL + k0 + q8];
        }
        __syncthreads();

        f16x8 a_h[4], b_h[4];
        #pragma unroll
        for (int i = 0; i < 4; i++)
            a_h[i] = *(const f16x8*)&Ah[(wr * 64 + i * 16 + li) * LSTR + g * 8];
        #pragma unroll
        for (int j = 0; j < 4; j++)
            b_h[j] = *(const f16x8*)&Bh[(wc * 64 + j * 16 + li) * LSTR + g * 8];
        #pragma unroll
        for (int i = 0; i < 4; i++)
            #pragma unroll
            for (int j = 0; j < 4; j++)
                acc[i][j] = __builtin_amdgcn_mfma_f32_16x16x32_f16(
                    b_h[j], a_h[i], acc[i][j], 0, 0, 0);   // C^T
        __syncthreads();
    }

    #pragma unroll
    for (int i = 0; i < 4; i++) {
        int grow = bm + wr * 64 + i * 16 + li;
        #pragma unroll
        for (int j = 0; j < 4; j++) {
            int gcol = bn + wc * 64 + j * 16 + g * 4;
            *(float4*)&O[(long)grow * DMODEL + gcol] = make_float4(
                acc[i][j][0], acc[i][j][1], acc[i][j][2], acc[i][j][3]);
        }
    }
}

// ------------------------- MFMA flash attention (fp16, S^T softmax) --------
// S^T = K·Q^T: each lane owns ONE query (col=li), 16 keys in regs.
// Staging is register-prefetched: next tile's K/V global loads issue during
// compute; only ds_writes sit between the barriers.
#define APAD 72
#define BIAS_LEN 2112

__global__ __launch_bounds__(256, 4) void attn_mfma(
    const u16* __restrict__ Qf, const u16* __restrict__ Kf,
    const u16* __restrict__ VT, const float* __restrict__ tab,
    u16* __restrict__ ctxb)
{
    __shared__ __align__(16) u16 Ks[64 * APAD];
    __shared__ __align__(16) u16 Vs[64 * APAD];    // [dim][key]
    __shared__ __align__(16) u16 Ps[64 * APAD];    // [q][key], wave-private rows
    __shared__ float biasL[BIAS_LEN];

    const int tid = threadIdx.x;
    const int wv = tid >> 6, lane = tid & 63;
    const int g = lane >> 4, li = lane & 15;
    const int qblk = blockIdx.x & 31;
    const int h = (blockIdx.x >> 5) & 15;
    const int b = blockIdx.x >> 9;
    const int q0 = qblk * 64;
    const long bh = b * NH + h;
    const int qloc = wv * 16 + li;     // this lane's query (within block)

    const u16* KhG = Kf + bh * (S_LEN * DK);
    const u16* VtG = VT + bh * (DK * S_LEN);
    const float* th = tab + h * 4096;

    // whole-block bias window: biasL[j] = th[2048 - q0 - 63 + j]
    // in-loop index j = kt0 + (key_in_tile) + 63 - qloc  ∈ [0, 2110]
    {
        const float* tb = th + 2048 - q0 - 63;
        for (int j = tid; j < BIAS_LEN; j += 256) biasL[j] = tb[j];
    }

    f16x8 q0f, q1f;
    {
        long qrow = bh * S_LEN + q0 + qloc;
        const u16* ph = Qf + qrow * DK + g * 8;
        q0f = *(const f16x8*)ph;  q1f = *(const f16x8*)(ph + 32);
    }

    f32x4 Oc[4];
    #pragma unroll
    for (int n = 0; n < 4; n++) Oc[n] = (f32x4){0.f, 0.f, 0.f, 0.f};
    float mP = -1e30f, lR = 0.f;

    // staging register prefetch (2 rows of K and V per thread)
    const int srow = tid >> 3, sc8 = (tid & 7) * 8;        // u=0
    const int srow1 = srow + 32;                           // u=1 (tid+256)
    uint4 kreg0, kreg1, vreg0, vreg1;
    kreg0 = *(const uint4*)&KhG[(long)srow * DK + sc8];
    kreg1 = *(const uint4*)&KhG[(long)srow1 * DK + sc8];
    vreg0 = *(const uint4*)&VtG[(long)srow * S_LEN + sc8];
    vreg1 = *(const uint4*)&VtG[(long)srow1 * S_LEN + sc8];

    for (int kt0 = 0; kt0 < S_LEN; kt0 += 64) {
        // ---- commit staged regs to LDS ----
        *(uint4*)&Ks[srow * APAD + sc8]  = kreg0;
        *(uint4*)&Ks[srow1 * APAD + sc8] = kreg1;
        *(uint4*)&Vs[srow * APAD + sc8]  = vreg0;
        *(uint4*)&Vs[srow1 * APAD + sc8] = vreg1;
        __syncthreads();

        // ---- prefetch next tile (overlaps with compute below) ----
        int nt = kt0 + 64;
        if (nt < S_LEN) {
            kreg0 = *(const uint4*)&KhG[(long)(nt + srow) * DK + sc8];
            kreg1 = *(const uint4*)&KhG[(long)(nt + srow1) * DK + sc8];
            vreg0 = *(const uint4*)&VtG[(long)srow * S_LEN + nt + sc8];
            vreg1 = *(const uint4*)&VtG[(long)srow1 * S_LEN + nt + sc8];
        }

        // ---- scores transposed: S^T[key][q] = K·Q^T ----
        f32x4 Sa[4];
        #pragma unroll
        for (int m = 0; m < 4; m++) {
            const u16* kp = &Ks[(m * 16 + li) * APAD + g * 8];
            f16x8 k0 = *(const f16x8*)kp, k1 = *(const f16x8*)(kp + 32);
            f32x4 s = (f32x4){0.f, 0.f, 0.f, 0.f};
            s = __builtin_amdgcn_mfma_f32_16x16x32_f16(k0, q0f, s, 0, 0, 0);
            s = __builtin_amdgcn_mfma_f32_16x16x32_f16(k1, q1f, s, 0, 0, 0);
            Sa[m] = s;   // rows: key = m*16 + g*4 + r ; col: query = li
        }

        // ---- bias ----
        const int jb = kt0 + g * 4 + 63 - qloc;
        #pragma unroll
        for (int m = 0; m < 4; m++)
            #pragma unroll
            for (int r = 0; r < 4; r++)
                Sa[m][r] += biasL[jb + m * 16 + r];

        // ---- online softmax: per-lane (one query), 16 keys in regs ----
        float pm = Sa[0][0];
        #pragma unroll
        for (int m = 0; m < 4; m++)
            #pragma unroll
            for (int r = 0; r < 4; r++) pm = fmaxf(pm, Sa[m][r]);
        pm = fmaxf(pm, __shfl_xor(pm, 16));
        pm = fmaxf(pm, __shfl_xor(pm, 32));

        float mn = fmaxf(mP, pm);
        float alpha = __expf(mP - mn);
        mP = mn;
        float aO[4];
        #pragma unroll
        for (int r = 0; r < 4; r++) aO[r] = __shfl(alpha, g * 4 + r);

        float ls = 0.f;
        #pragma unroll
        for (int m = 0; m < 4; m++)
            #pragma unroll
            for (int r = 0; r < 4; r++) {
                Sa[m][r] = __expf(Sa[m][r] - mn);
                ls += Sa[m][r];
            }
        ls += __shfl_xor(ls, 16);
        ls += __shfl_xor(ls, 32);
        lR = lR * alpha + ls;

        // ---- P -> LDS [q][key] via packed cvt; wave-private rows ----
        #pragma unroll
        for (int m = 0; m < 4; m++) {
            u32 lo = pkrtz(Sa[m][0], Sa[m][1]);
            u32 hi = pkrtz(Sa[m][2], Sa[m][3]);
            *(uint2*)&Ps[qloc * APAD + m * 16 + g * 4] = make_uint2(lo, hi);
        }

        // ---- Tc = P · V (independent of Oc), then Oc = Oc*alpha + Tc ----
        f32x4 Tc[4];
        #pragma unroll
        for (int n = 0; n < 4; n++) Tc[n] = (f32x4){0.f, 0.f, 0.f, 0.f};
        {
            const u16* pp = &Ps[qloc * APAD + g * 8];
            f16x8 p0 = *(const f16x8*)pp, p1 = *(const f16x8*)(pp + 32);
            #pragma unroll
            for (int n = 0; n < 4; n++) {
                const u16* vp = &Vs[(n * 16 + li) * APAD + g * 8];
                f16x8 v0 = *(const f16x8*)vp, v1 = *(const f16x8*)(vp + 32);
                Tc[n] = __builtin_amdgcn_mfma_f32_16x16x32_f16(p0, v0, Tc[n], 0, 0, 0);
                Tc[n] = __builtin_amdgcn_mfma_f32_16x16x32_f16(p1, v1, Tc[n], 0, 0, 0);
            }
        }
        #pragma unroll
        for (int n = 0; n < 4; n++)
            #pragma unroll
            for (int r = 0; r < 4; r++)
                Oc[n][r] = fmaf(Oc[n][r], aO[r], Tc[n][r]);

        __syncthreads();   // all waves done with Ks/Vs before next commit
    }

    float linv = 1.0f / lR;
    float iv[4];
    #pragma unroll
    for (int r = 0; r < 4; r++) iv[r] = __shfl(linv, g * 4 + r);
    #pragma unroll
    for (int n = 0; n < 4; n++)
        #pragma unroll
        for (int r = 0; r < 4; r++)
            ctxb[((long)(b * S_LEN + q0 + wv * 16 + g * 4 + r)) * DMODEL
                 + h * DK + n * 16 + li] = f2h(Oc[n][r] * iv[r]);
}

// ------------------------- launcher ----------------------------------------
extern "C" void kernel_launch(void* const* d_in, const int* in_sizes, int n_in,
                              void* d_out, int out_size, void* d_ws, size_t ws_size,
                              hipStream_t stream)
{
    const float* x    = (const float*)d_in[0];
    const float* wq   = (const float*)d_in[1];
    const float* wk   = (const float*)d_in[2];
    const float* wv   = (const float*)d_in[3];
    const float* wo   = (const float*)d_in[4];
    const float* rel  = (const float*)d_in[5];

    u16* W0 = (u16*)d_ws;
    u16* Xf  = W0;                          // fp16 x         (8 MB)
    u16* Qf  = W0 + 4194304;                // fp16 [B,H,S,Dk]
    u16* Kf  = W0 + 8388608;
    u16* VT  = W0 + 12582912;               // fp16 [B,H,Dk,S]
    u16* WT  = W0 + 16777216;               // 4 fp16 planes [n][k] (8 MB)
    float* tab = (float*)(W0 + 20971520);   // [16,4096] fp32
    u16* ctxb = Xf;                         // alias: Xf dead after gemm_qkv

    prep_kernel<<<dim3(3328), dim3(256), 0, stream>>>(x, wq, wk, wv, wo, rel,
                                                      Xf, WT, tab);
    gemm_qkv_mfma<<<dim3(8, 32, 3), dim3(256), 0, stream>>>(Xf, WT, Qf, Kf, VT);
    attn_mfma<<<dim3(1024), dim3(256), 0, stream>>>(Qf, Kf, VT, tab, ctxb);
    gemm_out_mfma<<<dim3(8, 32), dim3(256), 0, stream>>>(ctxb, WT, (float*)d_out);
}